// Round 1
// baseline (857.776 us; speedup 1.0000x reference)
//
#include <hip/hip_runtime.h>
#include <math.h>

#define N_NODES 50000
#define N_EDGES 800000
#define F 128
#define B_GRAPHS 64

// ---------------- utility ----------------

__global__ __launch_bounds__(256) void zero_i32(int* p, int n) {
    int i = blockIdx.x * blockDim.x + threadIdx.x;
    if (i < n) p[i] = 0;
}

// ---------------- degree / norm ----------------

__global__ __launch_bounds__(256) void deg_count(const int* __restrict__ dst,
                                                 int* __restrict__ deg) {
    int e = blockIdx.x * blockDim.x + threadIdx.x;
    if (e < N_EDGES) atomicAdd(&deg[dst[e]], 1);
}

__global__ __launch_bounds__(256) void dinv_kernel(const int* __restrict__ deg,
                                                   float* __restrict__ dinv) {
    int i = blockIdx.x * blockDim.x + threadIdx.x;
    if (i < N_NODES) dinv[i] = rsqrtf((float)(deg[i] + 1));  // +1 self-loop
}

// ---------------- CSR build ----------------

// single-block exclusive scan of deg -> off, cursor. 1024 threads.
__global__ __launch_bounds__(1024) void scan_kernel(const int* __restrict__ deg,
                                                    int* __restrict__ off,
                                                    int* __restrict__ cursor) {
    __shared__ int partial[1024];
    int t = threadIdx.x;
    const int C = (N_NODES + 1023) / 1024;  // 49
    int lo = t * C;
    int hi = lo + C; if (hi > N_NODES) hi = N_NODES;
    if (lo > N_NODES) lo = N_NODES;
    int s = 0;
    for (int i = lo; i < hi; ++i) s += deg[i];
    partial[t] = s;
    __syncthreads();
    // Hillis-Steele inclusive scan
    for (int d = 1; d < 1024; d <<= 1) {
        int v = (t >= d) ? partial[t - d] : 0;
        __syncthreads();
        partial[t] += v;
        __syncthreads();
    }
    int run = (t == 0) ? 0 : partial[t - 1];
    for (int i = lo; i < hi; ++i) {
        off[i] = run;
        cursor[i] = run;
        run += deg[i];
    }
    if (t == 1023) off[N_NODES] = partial[1023];
}

__global__ __launch_bounds__(256) void scatter_kernel(const int* __restrict__ src,
                                                      const int* __restrict__ dst,
                                                      int* __restrict__ cursor,
                                                      int* __restrict__ srcs) {
    int e = blockIdx.x * blockDim.x + threadIdx.x;
    if (e < N_EDGES) {
        int d = dst[e];
        int p = atomicAdd(&cursor[d], 1);
        srcs[p] = src[e];
    }
}

// ---------------- GEMM: out[i][c] = dinv[i] * sum_k X[i][k] W[k][c] ----------------
// M x 128 @ 128 x 128, block tile 128 rows x 128 cols, thread tile 8x8.

__global__ __launch_bounds__(256) void gemm_scale(const float* __restrict__ X,
                                                  const float* __restrict__ W,
                                                  const float* __restrict__ dinv,
                                                  float* __restrict__ out,
                                                  int nrows) {
    __shared__ float xT[32][F + 4];  // [k][row], padded
    __shared__ float wS[32][F];      // [k][col]
    const int block_row = blockIdx.x * 128;
    const int tid = threadIdx.x;
    const int rg = (tid >> 4) * 8;   // row group 0..120
    const int cg = (tid & 15) * 8;   // col group 0..120

    float acc[8][8];
#pragma unroll
    for (int i = 0; i < 8; ++i)
#pragma unroll
        for (int j = 0; j < 8; ++j) acc[i][j] = 0.f;

    for (int k0 = 0; k0 < F; k0 += 32) {
        // load X chunk (128 rows x 32 k), transposed into xT
#pragma unroll
        for (int l = 0; l < 4; ++l) {
            int idx = tid + l * 256;          // 0..1023
            int r = idx >> 3;                 // 0..127
            int kq = (idx & 7) * 4;           // 0,4,...,28
            int row = block_row + r;
            float4 v = make_float4(0.f, 0.f, 0.f, 0.f);
            if (row < nrows)
                v = *(const float4*)&X[(size_t)row * F + k0 + kq];
            xT[kq + 0][r] = v.x;
            xT[kq + 1][r] = v.y;
            xT[kq + 2][r] = v.z;
            xT[kq + 3][r] = v.w;
        }
        // load W chunk (32 k x 128 cols)
#pragma unroll
        for (int l = 0; l < 4; ++l) {
            int idx = tid + l * 256;          // 0..1023
            int kk = idx >> 5;                // 0..31
            int cq = (idx & 31) * 4;          // 0..124
            *(float4*)&wS[kk][cq] = *(const float4*)&W[(size_t)(k0 + kk) * F + cq];
        }
        __syncthreads();
#pragma unroll
        for (int k = 0; k < 32; ++k) {
            float a[8], bw[8];
            *(float4*)&a[0] = *(const float4*)&xT[k][rg];
            *(float4*)&a[4] = *(const float4*)&xT[k][rg + 4];
            *(float4*)&bw[0] = *(const float4*)&wS[k][cg];
            *(float4*)&bw[4] = *(const float4*)&wS[k][cg + 4];
#pragma unroll
            for (int i = 0; i < 8; ++i)
#pragma unroll
                for (int j = 0; j < 8; ++j)
                    acc[i][j] = fmaf(a[i], bw[j], acc[i][j]);
        }
        __syncthreads();
    }
#pragma unroll
    for (int i = 0; i < 8; ++i) {
        int row = block_row + rg + i;
        if (row < nrows) {
            float s = dinv[row];
            float4 o0 = make_float4(acc[i][0] * s, acc[i][1] * s, acc[i][2] * s, acc[i][3] * s);
            float4 o1 = make_float4(acc[i][4] * s, acc[i][5] * s, acc[i][6] * s, acc[i][7] * s);
            *(float4*)&out[(size_t)row * F + cg] = o0;
            *(float4*)&out[(size_t)row * F + cg + 4] = o1;
        }
    }
}

// ---------------- aggregation: out[i] = relu?(dinv[i]*(Hs[i] + sum Hs[src]) + b) ----------------

__global__ __launch_bounds__(128) void aggregate(const float* __restrict__ Hs,
                                                 const int* __restrict__ off,
                                                 const int* __restrict__ srcs,
                                                 const float* __restrict__ dinv,
                                                 const float* __restrict__ bias,
                                                 float* __restrict__ out,
                                                 int do_relu) {
    int i = blockIdx.x;
    int f = threadIdx.x;
    float acc = Hs[(size_t)i * F + f];  // self-loop term
    int e0 = off[i], e1 = off[i + 1];
    for (int e = e0; e < e1; ++e) {
        int s = srcs[e];
        acc += Hs[(size_t)s * F + f];
    }
    float v = fmaf(dinv[i], acc, bias[f]);
    if (do_relu) v = fmaxf(v, 0.f);
    out[(size_t)i * F + f] = v;
}

// ---------------- mean pool over sorted batch ids ----------------

__device__ __forceinline__ int lower_bound_dev(const int* __restrict__ a, int n, int v) {
    int lo = 0, hi = n;
    while (lo < hi) {
        int m = (lo + hi) >> 1;
        if (a[m] < v) lo = m + 1; else hi = m;
    }
    return lo;
}

__global__ __launch_bounds__(128) void pool_kernel(const float* __restrict__ H,
                                                   const int* __restrict__ batch,
                                                   float* __restrict__ g) {
    int b = blockIdx.x;
    int lo = lower_bound_dev(batch, N_NODES, b);
    int hi = lower_bound_dev(batch, N_NODES, b + 1);
    int f = threadIdx.x;
    float acc = 0.f;
    for (int i = lo; i < hi; ++i) acc += H[(size_t)i * F + f];
    float cnt = (float)(hi - lo);
    g[b * F + f] = acc / fmaxf(cnt, 1.0f);
}

// ---------------- head MLP: out[b] = relu(g fw1 + fb1) fw2 + fb2 ----------------

__global__ __launch_bounds__(64) void head_kernel(const float* __restrict__ g,
                                                  const float* __restrict__ fw1,
                                                  const float* __restrict__ fb1,
                                                  const float* __restrict__ fw2,
                                                  const float* __restrict__ fb2,
                                                  float* __restrict__ out) {
    int b = blockIdx.x;
    int j = threadIdx.x;  // 0..63 hidden unit
    float h = fb1[j];
    for (int k = 0; k < F; ++k)
        h = fmaf(g[b * F + k], fw1[k * 64 + j], h);
    h = fmaxf(h, 0.f) * fw2[j];
#pragma unroll
    for (int w = 32; w >= 1; w >>= 1) h += __shfl_xor(h, w, 64);
    if (j == 0) out[b] = h + fb2[0];
}

// ---------------- launcher ----------------

extern "C" void kernel_launch(void* const* d_in, const int* in_sizes, int n_in,
                              void* d_out, int out_size, void* d_ws, size_t ws_size,
                              hipStream_t stream) {
    const float* x    = (const float*)d_in[0];
    const int* eidx   = (const int*)d_in[1];
    const int* batch  = (const int*)d_in[2];
    const float* W1   = (const float*)d_in[3];
    const float* b1   = (const float*)d_in[4];
    const float* W2   = (const float*)d_in[5];
    const float* b2   = (const float*)d_in[6];
    const float* W3   = (const float*)d_in[7];
    const float* b3   = (const float*)d_in[8];
    const float* fw1  = (const float*)d_in[9];
    const float* fb1  = (const float*)d_in[10];
    const float* fw2  = (const float*)d_in[11];
    const float* fb2  = (const float*)d_in[12];
    float* out        = (float*)d_out;

    const int* src = eidx;            // edge_index[0]
    const int* dst = eidx + N_EDGES;  // edge_index[1]

    // workspace carve-up
    char* ws = (char*)d_ws;
    size_t p = 0;
    auto alloc = [&](size_t bytes) -> void* {
        void* r = ws + p;
        p = (p + bytes + 255) & ~(size_t)255;
        return r;
    };
    int*   deg    = (int*)  alloc((size_t)N_NODES * 4);
    float* dinv   = (float*)alloc((size_t)N_NODES * 4);
    int*   off    = (int*)  alloc((size_t)(N_NODES + 1) * 4);
    int*   cursor = (int*)  alloc((size_t)N_NODES * 4);
    int*   srcs   = (int*)  alloc((size_t)N_EDGES * 4);
    float* bufA   = (float*)alloc((size_t)N_NODES * F * 4);
    float* bufB   = (float*)alloc((size_t)N_NODES * F * 4);
    float* gpool  = (float*)alloc((size_t)B_GRAPHS * F * 4);
    (void)ws_size;

    const int TB = 256;
    const int nblk_N = (N_NODES + TB - 1) / TB;
    const int nblk_E = (N_EDGES + TB - 1) / TB;
    const int gemm_blocks = (N_NODES + 127) / 128;

    // 1. degrees
    zero_i32<<<nblk_N, TB, 0, stream>>>(deg, N_NODES);
    deg_count<<<nblk_E, TB, 0, stream>>>(dst, deg);
    dinv_kernel<<<nblk_N, TB, 0, stream>>>(deg, dinv);

    // 2. CSR
    scan_kernel<<<1, 1024, 0, stream>>>(deg, off, cursor);
    scatter_kernel<<<nblk_E, TB, 0, stream>>>(src, dst, cursor, srcs);

    // 3. layer 1: Hs = (x@W1)*dinv ; bufB = relu(dinv*(agg) + b1)
    gemm_scale<<<gemm_blocks, 256, 0, stream>>>(x, W1, dinv, bufA, N_NODES);
    aggregate<<<N_NODES, 128, 0, stream>>>(bufA, off, srcs, dinv, b1, bufB, 1);

    // 4. layer 2
    gemm_scale<<<gemm_blocks, 256, 0, stream>>>(bufB, W2, dinv, bufA, N_NODES);
    aggregate<<<N_NODES, 128, 0, stream>>>(bufA, off, srcs, dinv, b2, bufB, 1);

    // 5. layer 3 (no relu)
    gemm_scale<<<gemm_blocks, 256, 0, stream>>>(bufB, W3, dinv, bufA, N_NODES);
    aggregate<<<N_NODES, 128, 0, stream>>>(bufA, off, srcs, dinv, b3, bufB, 0);

    // 6. mean pool
    pool_kernel<<<B_GRAPHS, 128, 0, stream>>>(bufB, batch, gpool);

    // 7. head MLP
    head_kernel<<<B_GRAPHS, 64, 0, stream>>>(gpool, fw1, fb1, fw2, fb2, out);
}

// Round 2
// 727.211 us; speedup vs baseline: 1.1795x; 1.1795x over previous
//
#include <hip/hip_runtime.h>
#include <math.h>

#define N_NODES 50000
#define N_EDGES 800000
#define F 128
#define B_GRAPHS 64
#define POOL_CHUNK 256

// ---------------- utility ----------------

__global__ __launch_bounds__(256) void zero_i32(int* p, int n) {
    int i = blockIdx.x * blockDim.x + threadIdx.x;
    if (i < n) p[i] = 0;
}

// ---------------- degree / norm ----------------

__global__ __launch_bounds__(256) void deg_count(const int* __restrict__ dst,
                                                 int* __restrict__ deg) {
    int e = blockIdx.x * blockDim.x + threadIdx.x;
    if (e < N_EDGES) atomicAdd(&deg[dst[e]], 1);
}

__global__ __launch_bounds__(256) void dinv_kernel(const int* __restrict__ deg,
                                                   float* __restrict__ dinv) {
    int i = blockIdx.x * blockDim.x + threadIdx.x;
    if (i < N_NODES) dinv[i] = rsqrtf((float)(deg[i] + 1));  // +1 self-loop
}

// ---------------- CSR build ----------------

// single-block exclusive scan of deg -> off, cursor. 1024 threads.
__global__ __launch_bounds__(1024) void scan_kernel(const int* __restrict__ deg,
                                                    int* __restrict__ off,
                                                    int* __restrict__ cursor) {
    __shared__ int partial[1024];
    int t = threadIdx.x;
    const int C = (N_NODES + 1023) / 1024;  // 49
    int lo = t * C;
    int hi = lo + C; if (hi > N_NODES) hi = N_NODES;
    if (lo > N_NODES) lo = N_NODES;
    int s = 0;
    for (int i = lo; i < hi; ++i) s += deg[i];
    partial[t] = s;
    __syncthreads();
    // Hillis-Steele inclusive scan
    for (int d = 1; d < 1024; d <<= 1) {
        int v = (t >= d) ? partial[t - d] : 0;
        __syncthreads();
        partial[t] += v;
        __syncthreads();
    }
    int run = (t == 0) ? 0 : partial[t - 1];
    for (int i = lo; i < hi; ++i) {
        off[i] = run;
        cursor[i] = run;
        run += deg[i];
    }
    if (t == 1023) off[N_NODES] = partial[1023];
}

__global__ __launch_bounds__(256) void scatter_kernel(const int* __restrict__ src,
                                                      const int* __restrict__ dst,
                                                      int* __restrict__ cursor,
                                                      int* __restrict__ srcs) {
    int e = blockIdx.x * blockDim.x + threadIdx.x;
    if (e < N_EDGES) {
        int d = dst[e];
        int p = atomicAdd(&cursor[d], 1);
        srcs[p] = src[e];
    }
}

// ---------------- GEMM: out[i][c] = dinv[i] * sum_k X[i][k] W[k][c] ----------------
// M x 128 @ 128 x 128, block tile 128 rows x 128 cols, thread tile 8x8.

__global__ __launch_bounds__(256) void gemm_scale(const float* __restrict__ X,
                                                  const float* __restrict__ W,
                                                  const float* __restrict__ dinv,
                                                  float* __restrict__ out,
                                                  int nrows) {
    __shared__ float xT[32][F + 4];  // [k][row], padded
    __shared__ float wS[32][F];      // [k][col]
    const int block_row = blockIdx.x * 128;
    const int tid = threadIdx.x;
    const int rg = (tid >> 4) * 8;   // row group 0..120
    const int cg = (tid & 15) * 8;   // col group 0..120

    float acc[8][8];
#pragma unroll
    for (int i = 0; i < 8; ++i)
#pragma unroll
        for (int j = 0; j < 8; ++j) acc[i][j] = 0.f;

    for (int k0 = 0; k0 < F; k0 += 32) {
        // load X chunk (128 rows x 32 k), transposed into xT
#pragma unroll
        for (int l = 0; l < 4; ++l) {
            int idx = tid + l * 256;          // 0..1023
            int r = idx >> 3;                 // 0..127
            int kq = (idx & 7) * 4;           // 0,4,...,28
            int row = block_row + r;
            float4 v = make_float4(0.f, 0.f, 0.f, 0.f);
            if (row < nrows)
                v = *(const float4*)&X[(size_t)row * F + k0 + kq];
            xT[kq + 0][r] = v.x;
            xT[kq + 1][r] = v.y;
            xT[kq + 2][r] = v.z;
            xT[kq + 3][r] = v.w;
        }
        // load W chunk (32 k x 128 cols)
#pragma unroll
        for (int l = 0; l < 4; ++l) {
            int idx = tid + l * 256;          // 0..1023
            int kk = idx >> 5;                // 0..31
            int cq = (idx & 31) * 4;          // 0..124
            *(float4*)&wS[kk][cq] = *(const float4*)&W[(size_t)(k0 + kk) * F + cq];
        }
        __syncthreads();
#pragma unroll
        for (int k = 0; k < 32; ++k) {
            float a[8], bw[8];
            *(float4*)&a[0] = *(const float4*)&xT[k][rg];
            *(float4*)&a[4] = *(const float4*)&xT[k][rg + 4];
            *(float4*)&bw[0] = *(const float4*)&wS[k][cg];
            *(float4*)&bw[4] = *(const float4*)&wS[k][cg + 4];
#pragma unroll
            for (int i = 0; i < 8; ++i)
#pragma unroll
                for (int j = 0; j < 8; ++j)
                    acc[i][j] = fmaf(a[i], bw[j], acc[i][j]);
        }
        __syncthreads();
    }
#pragma unroll
    for (int i = 0; i < 8; ++i) {
        int row = block_row + rg + i;
        if (row < nrows) {
            float s = dinv[row];
            float4 o0 = make_float4(acc[i][0] * s, acc[i][1] * s, acc[i][2] * s, acc[i][3] * s);
            float4 o1 = make_float4(acc[i][4] * s, acc[i][5] * s, acc[i][6] * s, acc[i][7] * s);
            *(float4*)&out[(size_t)row * F + cg] = o0;
            *(float4*)&out[(size_t)row * F + cg + 4] = o1;
        }
    }
}

// ---------------- aggregation: out[i] = relu?(dinv[i]*(Hs[i] + sum Hs[src]) + b) ----------------

__global__ __launch_bounds__(128) void aggregate(const float* __restrict__ Hs,
                                                 const int* __restrict__ off,
                                                 const int* __restrict__ srcs,
                                                 const float* __restrict__ dinv,
                                                 const float* __restrict__ bias,
                                                 float* __restrict__ out,
                                                 int do_relu) {
    int i = blockIdx.x;
    int f = threadIdx.x;
    float acc = Hs[(size_t)i * F + f];  // self-loop term
    int e0 = off[i], e1 = off[i + 1];
    for (int e = e0; e < e1; ++e) {
        int s = srcs[e];
        acc += Hs[(size_t)s * F + f];
    }
    float v = fmaf(dinv[i], acc, bias[f]);
    if (do_relu) v = fmaxf(v, 0.f);
    out[(size_t)i * F + f] = v;
}

// ---------------- mean pool over sorted batch ids (parallel) ----------------

__global__ __launch_bounds__(256) void zero_f32(float* p, int n) {
    int i = blockIdx.x * blockDim.x + threadIdx.x;
    if (i < n) p[i] = 0.f;
}

// grid-strided over chunks of POOL_CHUNK nodes; run-length local accumulate,
// flush with one atomicAdd per (graph-run, feature).
__global__ __launch_bounds__(128) void pool_partial(const float* __restrict__ H,
                                                    const int* __restrict__ batch,
                                                    float* __restrict__ sums,
                                                    int* __restrict__ cnts) {
    int chunk0 = blockIdx.x * POOL_CHUNK;
    if (chunk0 >= N_NODES) return;
    int end = chunk0 + POOL_CHUNK;
    if (end > N_NODES) end = N_NODES;
    int f = threadIdx.x;
    float acc = 0.f;
    int cur = batch[chunk0];
    int runstart = chunk0;
    for (int i = chunk0; i < end; ++i) {
        int b = batch[i];
        if (b != cur) {
            atomicAdd(&sums[cur * F + f], acc);
            if (f == 0) atomicAdd(&cnts[cur], i - runstart);
            acc = 0.f;
            cur = b;
            runstart = i;
        }
        acc += H[(size_t)i * F + f];
    }
    atomicAdd(&sums[cur * F + f], acc);
    if (f == 0) atomicAdd(&cnts[cur], end - runstart);
}

__global__ __launch_bounds__(128) void pool_finalize(const float* __restrict__ sums,
                                                     const int* __restrict__ cnts,
                                                     float* __restrict__ g) {
    int b = blockIdx.x;
    int f = threadIdx.x;
    float cnt = (float)cnts[b];
    g[b * F + f] = sums[b * F + f] / fmaxf(cnt, 1.0f);
}

// ---------------- head MLP: out[b] = relu(g fw1 + fb1) fw2 + fb2 ----------------

__global__ __launch_bounds__(64) void head_kernel(const float* __restrict__ g,
                                                  const float* __restrict__ fw1,
                                                  const float* __restrict__ fb1,
                                                  const float* __restrict__ fw2,
                                                  const float* __restrict__ fb2,
                                                  float* __restrict__ out) {
    int b = blockIdx.x;
    int j = threadIdx.x;  // 0..63 hidden unit
    float h = fb1[j];
    for (int k = 0; k < F; ++k)
        h = fmaf(g[b * F + k], fw1[k * 64 + j], h);
    h = fmaxf(h, 0.f) * fw2[j];
#pragma unroll
    for (int w = 32; w >= 1; w >>= 1) h += __shfl_xor(h, w, 64);
    if (j == 0) out[b] = h + fb2[0];
}

// ---------------- launcher ----------------

extern "C" void kernel_launch(void* const* d_in, const int* in_sizes, int n_in,
                              void* d_out, int out_size, void* d_ws, size_t ws_size,
                              hipStream_t stream) {
    const float* x    = (const float*)d_in[0];
    const int* eidx   = (const int*)d_in[1];
    const int* batch  = (const int*)d_in[2];
    const float* W1   = (const float*)d_in[3];
    const float* b1   = (const float*)d_in[4];
    const float* W2   = (const float*)d_in[5];
    const float* b2   = (const float*)d_in[6];
    const float* W3   = (const float*)d_in[7];
    const float* b3   = (const float*)d_in[8];
    const float* fw1  = (const float*)d_in[9];
    const float* fb1  = (const float*)d_in[10];
    const float* fw2  = (const float*)d_in[11];
    const float* fb2  = (const float*)d_in[12];
    float* out        = (float*)d_out;

    const int* src = eidx;            // edge_index[0]
    const int* dst = eidx + N_EDGES;  // edge_index[1]

    // workspace carve-up
    char* ws = (char*)d_ws;
    size_t p = 0;
    auto alloc = [&](size_t bytes) -> void* {
        void* r = ws + p;
        p = (p + bytes + 255) & ~(size_t)255;
        return r;
    };
    int*   deg    = (int*)  alloc((size_t)N_NODES * 4);
    float* dinv   = (float*)alloc((size_t)N_NODES * 4);
    int*   off    = (int*)  alloc((size_t)(N_NODES + 1) * 4);
    int*   cursor = (int*)  alloc((size_t)N_NODES * 4);
    int*   srcs   = (int*)  alloc((size_t)N_EDGES * 4);
    float* bufA   = (float*)alloc((size_t)N_NODES * F * 4);
    float* bufB   = (float*)alloc((size_t)N_NODES * F * 4);
    float* psums  = (float*)alloc((size_t)B_GRAPHS * F * 4);
    int*   pcnts  = (int*)  alloc((size_t)B_GRAPHS * 4);
    float* gpool  = (float*)alloc((size_t)B_GRAPHS * F * 4);
    (void)ws_size;

    const int TB = 256;
    const int nblk_N = (N_NODES + TB - 1) / TB;
    const int nblk_E = (N_EDGES + TB - 1) / TB;
    const int gemm_blocks = (N_NODES + 127) / 128;
    const int pool_blocks = (N_NODES + POOL_CHUNK - 1) / POOL_CHUNK;

    // 1. degrees
    zero_i32<<<nblk_N, TB, 0, stream>>>(deg, N_NODES);
    deg_count<<<nblk_E, TB, 0, stream>>>(dst, deg);
    dinv_kernel<<<nblk_N, TB, 0, stream>>>(deg, dinv);

    // 2. CSR
    scan_kernel<<<1, 1024, 0, stream>>>(deg, off, cursor);
    scatter_kernel<<<nblk_E, TB, 0, stream>>>(src, dst, cursor, srcs);

    // 3. layer 1: Hs = (x@W1)*dinv ; bufB = relu(dinv*(agg) + b1)
    gemm_scale<<<gemm_blocks, 256, 0, stream>>>(x, W1, dinv, bufA, N_NODES);
    aggregate<<<N_NODES, 128, 0, stream>>>(bufA, off, srcs, dinv, b1, bufB, 1);

    // 4. layer 2
    gemm_scale<<<gemm_blocks, 256, 0, stream>>>(bufB, W2, dinv, bufA, N_NODES);
    aggregate<<<N_NODES, 128, 0, stream>>>(bufA, off, srcs, dinv, b2, bufB, 1);

    // 5. layer 3 (no relu)
    gemm_scale<<<gemm_blocks, 256, 0, stream>>>(bufB, W3, dinv, bufA, N_NODES);
    aggregate<<<N_NODES, 128, 0, stream>>>(bufA, off, srcs, dinv, b3, bufB, 0);

    // 6. mean pool (parallel two-stage)
    zero_f32<<<(B_GRAPHS * F + TB - 1) / TB, TB, 0, stream>>>(psums, B_GRAPHS * F);
    zero_i32<<<1, B_GRAPHS, 0, stream>>>(pcnts, B_GRAPHS);
    pool_partial<<<pool_blocks, 128, 0, stream>>>(bufB, batch, psums, pcnts);
    pool_finalize<<<B_GRAPHS, 128, 0, stream>>>(psums, pcnts, gpool);

    // 7. head MLP
    head_kernel<<<B_GRAPHS, 64, 0, stream>>>(gpool, fw1, fb1, fw2, fb2, out);
}

// Round 3
// 624.550 us; speedup vs baseline: 1.3734x; 1.1644x over previous
//
#include <hip/hip_runtime.h>
#include <math.h>

#define N_NODES 50000
#define N_EDGES 800000
#define F 128
#define B_GRAPHS 64
#define POOL_CHUNK 256
#define SCAN_NB 49          // ceil(50000 / 1024)
#define N_INT4 12500        // N_NODES / 4

// ---------------- utility ----------------

__global__ __launch_bounds__(256) void zero_i32(int* p, int n) {
    int i = blockIdx.x * blockDim.x + threadIdx.x;
    if (i < n) p[i] = 0;
}

// ---------------- degree / norm ----------------

__global__ __launch_bounds__(256) void deg_count(const int* __restrict__ dst,
                                                 int* __restrict__ deg) {
    int e = blockIdx.x * blockDim.x + threadIdx.x;
    if (e < N_EDGES) atomicAdd(&deg[dst[e]], 1);
}

__global__ __launch_bounds__(256) void dinv_kernel(const int* __restrict__ deg,
                                                   float* __restrict__ dinv) {
    int i = blockIdx.x * blockDim.x + threadIdx.x;
    if (i < N_NODES) dinv[i] = rsqrtf((float)(deg[i] + 1));  // +1 self-loop
}

// ---------------- CSR build: two-level scan ----------------

// Each block: 256 threads x int4 = 1024 nodes. Coalesced loads, wave shuffle
// scan, cross-wave LDS combine. Writes block-local exclusive offsets + bsum.
__global__ __launch_bounds__(256) void scan1(const int* __restrict__ deg,
                                             int* __restrict__ off,
                                             int* __restrict__ bsum) {
    __shared__ int wsum[4];
    int b = blockIdx.x, t = threadIdx.x;
    int i4 = b * 256 + t;
    int4 v = make_int4(0, 0, 0, 0);
    if (i4 < N_INT4) v = ((const int4*)deg)[i4];
    int s = v.x + v.y + v.z + v.w;
    int lane = t & 63;
    int incl = s;
#pragma unroll
    for (int d = 1; d < 64; d <<= 1) {
        int u = __shfl_up(incl, d, 64);
        if (lane >= d) incl += u;
    }
    int wave = t >> 6;
    if (lane == 63) wsum[wave] = incl;
    __syncthreads();
    int woff = 0;
#pragma unroll
    for (int w = 0; w < 3; ++w) if (w < wave) woff += wsum[w];
    int texcl = woff + incl - s;
    int4 o;
    o.x = texcl;
    o.y = o.x + v.x;
    o.z = o.y + v.y;
    o.w = o.z + v.z;
    if (i4 < N_INT4) ((int4*)off)[i4] = o;
    if (t == 255) bsum[b] = woff + incl;  // block total
}

__global__ __launch_bounds__(64) void scan2(const int* __restrict__ bsum,
                                            int* __restrict__ bexcl,
                                            int* __restrict__ off) {
    int t = threadIdx.x;
    int v = (t < SCAN_NB) ? bsum[t] : 0;
    int incl = v;
#pragma unroll
    for (int d = 1; d < 64; d <<= 1) {
        int u = __shfl_up(incl, d, 64);
        if (t >= d) incl += u;
    }
    if (t < SCAN_NB) bexcl[t] = incl - v;
    if (t == 63) off[N_NODES] = incl;  // grand total (= N_EDGES)
}

__global__ __launch_bounds__(256) void scan3(int* __restrict__ off,
                                             int* __restrict__ cursor,
                                             const int* __restrict__ bexcl) {
    int b = blockIdx.x, t = threadIdx.x;
    int i4 = b * 256 + t;
    if (i4 >= N_INT4) return;
    int add = bexcl[b];
    int4 o = ((int4*)off)[i4];
    o.x += add; o.y += add; o.z += add; o.w += add;
    ((int4*)off)[i4] = o;
    ((int4*)cursor)[i4] = o;
}

__global__ __launch_bounds__(256) void scatter_kernel(const int* __restrict__ src,
                                                      const int* __restrict__ dst,
                                                      int* __restrict__ cursor,
                                                      int* __restrict__ srcs) {
    int e = blockIdx.x * blockDim.x + threadIdx.x;
    if (e < N_EDGES) {
        int d = dst[e];
        int p = atomicAdd(&cursor[d], 1);
        srcs[p] = src[e];
    }
}

// ---------------- GEMM: out[i][c] = dinv[i] * sum_k X[i][k] W[k][c] ----------------
// M x 128 @ 128 x 128, block tile 128 rows x 128 cols, thread tile 8x8.

__global__ __launch_bounds__(256) void gemm_scale(const float* __restrict__ X,
                                                  const float* __restrict__ W,
                                                  const float* __restrict__ dinv,
                                                  float* __restrict__ out,
                                                  int nrows) {
    __shared__ float xT[32][F + 4];  // [k][row], padded
    __shared__ float wS[32][F];      // [k][col]
    const int block_row = blockIdx.x * 128;
    const int tid = threadIdx.x;
    const int rg = (tid >> 4) * 8;   // row group 0..120
    const int cg = (tid & 15) * 8;   // col group 0..120

    float acc[8][8];
#pragma unroll
    for (int i = 0; i < 8; ++i)
#pragma unroll
        for (int j = 0; j < 8; ++j) acc[i][j] = 0.f;

    for (int k0 = 0; k0 < F; k0 += 32) {
        // load X chunk (128 rows x 32 k), transposed into xT
#pragma unroll
        for (int l = 0; l < 4; ++l) {
            int idx = tid + l * 256;          // 0..1023
            int r = idx >> 3;                 // 0..127
            int kq = (idx & 7) * 4;           // 0,4,...,28
            int row = block_row + r;
            float4 v = make_float4(0.f, 0.f, 0.f, 0.f);
            if (row < nrows)
                v = *(const float4*)&X[(size_t)row * F + k0 + kq];
            xT[kq + 0][r] = v.x;
            xT[kq + 1][r] = v.y;
            xT[kq + 2][r] = v.z;
            xT[kq + 3][r] = v.w;
        }
        // load W chunk (32 k x 128 cols)
#pragma unroll
        for (int l = 0; l < 4; ++l) {
            int idx = tid + l * 256;          // 0..1023
            int kk = idx >> 5;                // 0..31
            int cq = (idx & 31) * 4;          // 0..124
            *(float4*)&wS[kk][cq] = *(const float4*)&W[(size_t)(k0 + kk) * F + cq];
        }
        __syncthreads();
#pragma unroll
        for (int k = 0; k < 32; ++k) {
            float a[8], bw[8];
            *(float4*)&a[0] = *(const float4*)&xT[k][rg];
            *(float4*)&a[4] = *(const float4*)&xT[k][rg + 4];
            *(float4*)&bw[0] = *(const float4*)&wS[k][cg];
            *(float4*)&bw[4] = *(const float4*)&wS[k][cg + 4];
#pragma unroll
            for (int i = 0; i < 8; ++i)
#pragma unroll
                for (int j = 0; j < 8; ++j)
                    acc[i][j] = fmaf(a[i], bw[j], acc[i][j]);
        }
        __syncthreads();
    }
#pragma unroll
    for (int i = 0; i < 8; ++i) {
        int row = block_row + rg + i;
        if (row < nrows) {
            float s = dinv[row];
            float4 o0 = make_float4(acc[i][0] * s, acc[i][1] * s, acc[i][2] * s, acc[i][3] * s);
            float4 o1 = make_float4(acc[i][4] * s, acc[i][5] * s, acc[i][6] * s, acc[i][7] * s);
            *(float4*)&out[(size_t)row * F + cg] = o0;
            *(float4*)&out[(size_t)row * F + cg + 4] = o1;
        }
    }
}

// ---------------- aggregation: out[i] = relu?(dinv[i]*(Hs[i] + sum Hs[src]) + b) ----------------

__global__ __launch_bounds__(128) void aggregate(const float* __restrict__ Hs,
                                                 const int* __restrict__ off,
                                                 const int* __restrict__ srcs,
                                                 const float* __restrict__ dinv,
                                                 const float* __restrict__ bias,
                                                 float* __restrict__ out,
                                                 int do_relu) {
    int i = blockIdx.x;
    int f = threadIdx.x;
    float acc = Hs[(size_t)i * F + f];  // self-loop term
    int e0 = off[i], e1 = off[i + 1];
    for (int e = e0; e < e1; ++e) {
        int s = srcs[e];
        acc += Hs[(size_t)s * F + f];
    }
    float v = fmaf(dinv[i], acc, bias[f]);
    if (do_relu) v = fmaxf(v, 0.f);
    out[(size_t)i * F + f] = v;
}

// ---------------- mean pool over sorted batch ids (parallel) ----------------

__global__ __launch_bounds__(256) void zero_f32(float* p, int n) {
    int i = blockIdx.x * blockDim.x + threadIdx.x;
    if (i < n) p[i] = 0.f;
}

__global__ __launch_bounds__(128) void pool_partial(const float* __restrict__ H,
                                                    const int* __restrict__ batch,
                                                    float* __restrict__ sums,
                                                    int* __restrict__ cnts) {
    int chunk0 = blockIdx.x * POOL_CHUNK;
    if (chunk0 >= N_NODES) return;
    int end = chunk0 + POOL_CHUNK;
    if (end > N_NODES) end = N_NODES;
    int f = threadIdx.x;
    float acc = 0.f;
    int cur = batch[chunk0];
    int runstart = chunk0;
    for (int i = chunk0; i < end; ++i) {
        int b = batch[i];
        if (b != cur) {
            atomicAdd(&sums[cur * F + f], acc);
            if (f == 0) atomicAdd(&cnts[cur], i - runstart);
            acc = 0.f;
            cur = b;
            runstart = i;
        }
        acc += H[(size_t)i * F + f];
    }
    atomicAdd(&sums[cur * F + f], acc);
    if (f == 0) atomicAdd(&cnts[cur], end - runstart);
}

__global__ __launch_bounds__(128) void pool_finalize(const float* __restrict__ sums,
                                                     const int* __restrict__ cnts,
                                                     float* __restrict__ g) {
    int b = blockIdx.x;
    int f = threadIdx.x;
    float cnt = (float)cnts[b];
    g[b * F + f] = sums[b * F + f] / fmaxf(cnt, 1.0f);
}

// ---------------- head MLP: out[b] = relu(g fw1 + fb1) fw2 + fb2 ----------------

__global__ __launch_bounds__(64) void head_kernel(const float* __restrict__ g,
                                                  const float* __restrict__ fw1,
                                                  const float* __restrict__ fb1,
                                                  const float* __restrict__ fw2,
                                                  const float* __restrict__ fb2,
                                                  float* __restrict__ out) {
    int b = blockIdx.x;
    int j = threadIdx.x;  // 0..63 hidden unit
    float h = fb1[j];
    for (int k = 0; k < F; ++k)
        h = fmaf(g[b * F + k], fw1[k * 64 + j], h);
    h = fmaxf(h, 0.f) * fw2[j];
#pragma unroll
    for (int w = 32; w >= 1; w >>= 1) h += __shfl_xor(h, w, 64);
    if (j == 0) out[b] = h + fb2[0];
}

// ---------------- launcher ----------------

extern "C" void kernel_launch(void* const* d_in, const int* in_sizes, int n_in,
                              void* d_out, int out_size, void* d_ws, size_t ws_size,
                              hipStream_t stream) {
    const float* x    = (const float*)d_in[0];
    const int* eidx   = (const int*)d_in[1];
    const int* batch  = (const int*)d_in[2];
    const float* W1   = (const float*)d_in[3];
    const float* b1   = (const float*)d_in[4];
    const float* W2   = (const float*)d_in[5];
    const float* b2   = (const float*)d_in[6];
    const float* W3   = (const float*)d_in[7];
    const float* b3   = (const float*)d_in[8];
    const float* fw1  = (const float*)d_in[9];
    const float* fb1  = (const float*)d_in[10];
    const float* fw2  = (const float*)d_in[11];
    const float* fb2  = (const float*)d_in[12];
    float* out        = (float*)d_out;

    const int* src = eidx;            // edge_index[0]
    const int* dst = eidx + N_EDGES;  // edge_index[1]

    // workspace carve-up
    char* ws = (char*)d_ws;
    size_t p = 0;
    auto alloc = [&](size_t bytes) -> void* {
        void* r = ws + p;
        p = (p + bytes + 255) & ~(size_t)255;
        return r;
    };
    int*   deg    = (int*)  alloc((size_t)N_NODES * 4);
    float* dinv   = (float*)alloc((size_t)N_NODES * 4);
    int*   off    = (int*)  alloc((size_t)(N_NODES + 4) * 4);
    int*   cursor = (int*)  alloc((size_t)N_NODES * 4);
    int*   srcs   = (int*)  alloc((size_t)N_EDGES * 4);
    int*   bsum   = (int*)  alloc((size_t)SCAN_NB * 4);
    int*   bexcl  = (int*)  alloc((size_t)SCAN_NB * 4);
    float* bufA   = (float*)alloc((size_t)N_NODES * F * 4);
    float* bufB   = (float*)alloc((size_t)N_NODES * F * 4);
    float* psums  = (float*)alloc((size_t)B_GRAPHS * F * 4);
    int*   pcnts  = (int*)  alloc((size_t)B_GRAPHS * 4);
    float* gpool  = (float*)alloc((size_t)B_GRAPHS * F * 4);
    (void)ws_size;

    const int TB = 256;
    const int nblk_N = (N_NODES + TB - 1) / TB;
    const int nblk_E = (N_EDGES + TB - 1) / TB;
    const int gemm_blocks = (N_NODES + 127) / 128;
    const int pool_blocks = (N_NODES + POOL_CHUNK - 1) / POOL_CHUNK;

    // 1. degrees
    zero_i32<<<nblk_N, TB, 0, stream>>>(deg, N_NODES);
    deg_count<<<nblk_E, TB, 0, stream>>>(dst, deg);
    dinv_kernel<<<nblk_N, TB, 0, stream>>>(deg, dinv);

    // 2. CSR (two-level scan + scatter)
    scan1<<<SCAN_NB, 256, 0, stream>>>(deg, off, bsum);
    scan2<<<1, 64, 0, stream>>>(bsum, bexcl, off);
    scan3<<<SCAN_NB, 256, 0, stream>>>(off, cursor, bexcl);
    scatter_kernel<<<nblk_E, TB, 0, stream>>>(src, dst, cursor, srcs);

    // 3. layer 1: Hs = (x@W1)*dinv ; bufB = relu(dinv*(agg) + b1)
    gemm_scale<<<gemm_blocks, 256, 0, stream>>>(x, W1, dinv, bufA, N_NODES);
    aggregate<<<N_NODES, 128, 0, stream>>>(bufA, off, srcs, dinv, b1, bufB, 1);

    // 4. layer 2
    gemm_scale<<<gemm_blocks, 256, 0, stream>>>(bufB, W2, dinv, bufA, N_NODES);
    aggregate<<<N_NODES, 128, 0, stream>>>(bufA, off, srcs, dinv, b2, bufB, 1);

    // 5. layer 3 (no relu)
    gemm_scale<<<gemm_blocks, 256, 0, stream>>>(bufB, W3, dinv, bufA, N_NODES);
    aggregate<<<N_NODES, 128, 0, stream>>>(bufA, off, srcs, dinv, b3, bufB, 0);

    // 6. mean pool (parallel two-stage)
    zero_f32<<<(B_GRAPHS * F + TB - 1) / TB, TB, 0, stream>>>(psums, B_GRAPHS * F);
    zero_i32<<<1, B_GRAPHS, 0, stream>>>(pcnts, B_GRAPHS);
    pool_partial<<<pool_blocks, 128, 0, stream>>>(bufB, batch, psums, pcnts);
    pool_finalize<<<B_GRAPHS, 128, 0, stream>>>(psums, pcnts, gpool);

    // 7. head MLP
    head_kernel<<<B_GRAPHS, 64, 0, stream>>>(gpool, fw1, fb1, fw2, fb2, out);
}

// Round 4
// 526.172 us; speedup vs baseline: 1.6302x; 1.1870x over previous
//
#include <hip/hip_runtime.h>
#include <math.h>

#define N_NODES 50000
#define N_EDGES 800000
#define F 128
#define FH 64               // packed bf16x2 words per row
#define B_GRAPHS 64
#define POOL_CHUNK 256
#define SCAN_NB 49          // ceil(50000 / 1024)
#define N_INT4 12500        // N_NODES / 4

// ---------------- bf16 pack/unpack ----------------

__device__ __forceinline__ unsigned pack_bf16x2(float a, float b) {
    unsigned ua = __float_as_uint(a);
    unsigned ub = __float_as_uint(b);
    ua += 0x7fffu + ((ua >> 16) & 1u);   // RNE
    ub += 0x7fffu + ((ub >> 16) & 1u);
    return (ua >> 16) | (ub & 0xffff0000u);
}

__device__ __forceinline__ float2 unpack_bf16x2(unsigned p) {
    return make_float2(__uint_as_float(p << 16),
                       __uint_as_float(p & 0xffff0000u));
}

// ---------------- utility ----------------

__global__ __launch_bounds__(256) void zero_i32(int* p, int n) {
    int i = blockIdx.x * blockDim.x + threadIdx.x;
    if (i < n) p[i] = 0;
}

// ---------------- degree / norm ----------------

__global__ __launch_bounds__(256) void deg_count(const int* __restrict__ dst,
                                                 int* __restrict__ deg) {
    int e = blockIdx.x * blockDim.x + threadIdx.x;
    if (e < N_EDGES) atomicAdd(&deg[dst[e]], 1);
}

__global__ __launch_bounds__(256) void dinv_kernel(const int* __restrict__ deg,
                                                   float* __restrict__ dinv) {
    int i = blockIdx.x * blockDim.x + threadIdx.x;
    if (i < N_NODES) dinv[i] = rsqrtf((float)(deg[i] + 1));  // +1 self-loop
}

// ---------------- CSR build: two-level scan ----------------

__global__ __launch_bounds__(256) void scan1(const int* __restrict__ deg,
                                             int* __restrict__ off,
                                             int* __restrict__ bsum) {
    __shared__ int wsum[4];
    int b = blockIdx.x, t = threadIdx.x;
    int i4 = b * 256 + t;
    int4 v = make_int4(0, 0, 0, 0);
    if (i4 < N_INT4) v = ((const int4*)deg)[i4];
    int s = v.x + v.y + v.z + v.w;
    int lane = t & 63;
    int incl = s;
#pragma unroll
    for (int d = 1; d < 64; d <<= 1) {
        int u = __shfl_up(incl, d, 64);
        if (lane >= d) incl += u;
    }
    int wave = t >> 6;
    if (lane == 63) wsum[wave] = incl;
    __syncthreads();
    int woff = 0;
#pragma unroll
    for (int w = 0; w < 3; ++w) if (w < wave) woff += wsum[w];
    int texcl = woff + incl - s;
    int4 o;
    o.x = texcl;
    o.y = o.x + v.x;
    o.z = o.y + v.y;
    o.w = o.z + v.z;
    if (i4 < N_INT4) ((int4*)off)[i4] = o;
    if (t == 255) bsum[b] = woff + incl;  // block total
}

__global__ __launch_bounds__(64) void scan2(const int* __restrict__ bsum,
                                            int* __restrict__ bexcl,
                                            int* __restrict__ off) {
    int t = threadIdx.x;
    int v = (t < SCAN_NB) ? bsum[t] : 0;
    int incl = v;
#pragma unroll
    for (int d = 1; d < 64; d <<= 1) {
        int u = __shfl_up(incl, d, 64);
        if (t >= d) incl += u;
    }
    if (t < SCAN_NB) bexcl[t] = incl - v;
    if (t == 63) off[N_NODES] = incl;  // grand total (= N_EDGES)
}

__global__ __launch_bounds__(256) void scan3(int* __restrict__ off,
                                             int* __restrict__ cursor,
                                             const int* __restrict__ bexcl) {
    int b = blockIdx.x, t = threadIdx.x;
    int i4 = b * 256 + t;
    if (i4 >= N_INT4) return;
    int add = bexcl[b];
    int4 o = ((int4*)off)[i4];
    o.x += add; o.y += add; o.z += add; o.w += add;
    ((int4*)off)[i4] = o;
    ((int4*)cursor)[i4] = o;
}

__global__ __launch_bounds__(256) void scatter_kernel(const int* __restrict__ src,
                                                      const int* __restrict__ dst,
                                                      int* __restrict__ cursor,
                                                      int* __restrict__ srcs) {
    int e = blockIdx.x * blockDim.x + threadIdx.x;
    if (e < N_EDGES) {
        int d = dst[e];
        int p = atomicAdd(&cursor[d], 1);
        srcs[p] = src[e];
    }
}

// ---------------- GEMM: Hs[i][c] = bf16( dinv[i] * sum_k X[i][k] W[k][c] ) ----------------
// M x 128 @ 128 x 128, block tile 128 rows x 128 cols, thread tile 8x8.

__global__ __launch_bounds__(256) void gemm_scale(const float* __restrict__ X,
                                                  const float* __restrict__ W,
                                                  const float* __restrict__ dinv,
                                                  unsigned* __restrict__ outp,  // packed bf16x2 [nrows][64]
                                                  int nrows) {
    __shared__ float xT[32][F + 4];  // [k][row], padded
    __shared__ float wS[32][F];      // [k][col]
    const int block_row = blockIdx.x * 128;
    const int tid = threadIdx.x;
    const int rg = (tid >> 4) * 8;   // row group 0..120
    const int cg = (tid & 15) * 8;   // col group 0..120

    float acc[8][8];
#pragma unroll
    for (int i = 0; i < 8; ++i)
#pragma unroll
        for (int j = 0; j < 8; ++j) acc[i][j] = 0.f;

    for (int k0 = 0; k0 < F; k0 += 32) {
#pragma unroll
        for (int l = 0; l < 4; ++l) {
            int idx = tid + l * 256;          // 0..1023
            int r = idx >> 3;                 // 0..127
            int kq = (idx & 7) * 4;           // 0,4,...,28
            int row = block_row + r;
            float4 v = make_float4(0.f, 0.f, 0.f, 0.f);
            if (row < nrows)
                v = *(const float4*)&X[(size_t)row * F + k0 + kq];
            xT[kq + 0][r] = v.x;
            xT[kq + 1][r] = v.y;
            xT[kq + 2][r] = v.z;
            xT[kq + 3][r] = v.w;
        }
#pragma unroll
        for (int l = 0; l < 4; ++l) {
            int idx = tid + l * 256;          // 0..1023
            int kk = idx >> 5;                // 0..31
            int cq = (idx & 31) * 4;          // 0..124
            *(float4*)&wS[kk][cq] = *(const float4*)&W[(size_t)(k0 + kk) * F + cq];
        }
        __syncthreads();
#pragma unroll
        for (int k = 0; k < 32; ++k) {
            float a[8], bw[8];
            *(float4*)&a[0] = *(const float4*)&xT[k][rg];
            *(float4*)&a[4] = *(const float4*)&xT[k][rg + 4];
            *(float4*)&bw[0] = *(const float4*)&wS[k][cg];
            *(float4*)&bw[4] = *(const float4*)&wS[k][cg + 4];
#pragma unroll
            for (int i = 0; i < 8; ++i)
#pragma unroll
                for (int j = 0; j < 8; ++j)
                    acc[i][j] = fmaf(a[i], bw[j], acc[i][j]);
        }
        __syncthreads();
    }
#pragma unroll
    for (int i = 0; i < 8; ++i) {
        int row = block_row + rg + i;
        if (row < nrows) {
            float s = dinv[row];
            uint4 o;
            o.x = pack_bf16x2(acc[i][0] * s, acc[i][1] * s);
            o.y = pack_bf16x2(acc[i][2] * s, acc[i][3] * s);
            o.z = pack_bf16x2(acc[i][4] * s, acc[i][5] * s);
            o.w = pack_bf16x2(acc[i][6] * s, acc[i][7] * s);
            *(uint4*)&outp[(size_t)row * FH + (cg >> 1)] = o;
        }
    }
}

// ------- aggregation: out[i] = relu?(dinv[i]*(Hs[i] + sum Hs[src]) + b), Hs packed bf16 -------
// one 64-lane wave per node; lane owns features 2*lane, 2*lane+1.

__global__ __launch_bounds__(256) void aggregate_bf16(const unsigned* __restrict__ Hs,
                                                      const int* __restrict__ off,
                                                      const int* __restrict__ srcs,
                                                      const float* __restrict__ dinv,
                                                      const float* __restrict__ bias,
                                                      float* __restrict__ out,
                                                      int do_relu) {
    int node = blockIdx.x * 4 + (threadIdx.x >> 6);
    if (node >= N_NODES) return;
    int lane = threadIdx.x & 63;

    float2 acc = unpack_bf16x2(Hs[(size_t)node * FH + lane]);  // self term
    int e0 = off[node], e1 = off[node + 1];
    int e = e0;
    for (; e + 1 < e1; e += 2) {
        int s0 = srcs[e], s1 = srcs[e + 1];
        unsigned p0 = Hs[(size_t)s0 * FH + lane];
        unsigned p1 = Hs[(size_t)s1 * FH + lane];
        float2 v0 = unpack_bf16x2(p0);
        float2 v1 = unpack_bf16x2(p1);
        acc.x += v0.x + v1.x;
        acc.y += v0.y + v1.y;
    }
    if (e < e1) {
        float2 v = unpack_bf16x2(Hs[(size_t)srcs[e] * FH + lane]);
        acc.x += v.x;
        acc.y += v.y;
    }
    float d = dinv[node];
    float o0 = fmaf(d, acc.x, bias[2 * lane]);
    float o1 = fmaf(d, acc.y, bias[2 * lane + 1]);
    if (do_relu) { o0 = fmaxf(o0, 0.f); o1 = fmaxf(o1, 0.f); }
    *(float2*)&out[(size_t)node * F + 2 * lane] = make_float2(o0, o1);
}

// ---------------- mean pool over sorted batch ids (parallel) ----------------

__global__ __launch_bounds__(256) void zero_f32(float* p, int n) {
    int i = blockIdx.x * blockDim.x + threadIdx.x;
    if (i < n) p[i] = 0.f;
}

__global__ __launch_bounds__(128) void pool_partial(const float* __restrict__ H,
                                                    const int* __restrict__ batch,
                                                    float* __restrict__ sums,
                                                    int* __restrict__ cnts) {
    int chunk0 = blockIdx.x * POOL_CHUNK;
    if (chunk0 >= N_NODES) return;
    int end = chunk0 + POOL_CHUNK;
    if (end > N_NODES) end = N_NODES;
    int f = threadIdx.x;
    float acc = 0.f;
    int cur = batch[chunk0];
    int runstart = chunk0;
    for (int i = chunk0; i < end; ++i) {
        int b = batch[i];
        if (b != cur) {
            atomicAdd(&sums[cur * F + f], acc);
            if (f == 0) atomicAdd(&cnts[cur], i - runstart);
            acc = 0.f;
            cur = b;
            runstart = i;
        }
        acc += H[(size_t)i * F + f];
    }
    atomicAdd(&sums[cur * F + f], acc);
    if (f == 0) atomicAdd(&cnts[cur], end - runstart);
}

__global__ __launch_bounds__(128) void pool_finalize(const float* __restrict__ sums,
                                                     const int* __restrict__ cnts,
                                                     float* __restrict__ g) {
    int b = blockIdx.x;
    int f = threadIdx.x;
    float cnt = (float)cnts[b];
    g[b * F + f] = sums[b * F + f] / fmaxf(cnt, 1.0f);
}

// ---------------- head MLP: out[b] = relu(g fw1 + fb1) fw2 + fb2 ----------------

__global__ __launch_bounds__(64) void head_kernel(const float* __restrict__ g,
                                                  const float* __restrict__ fw1,
                                                  const float* __restrict__ fb1,
                                                  const float* __restrict__ fw2,
                                                  const float* __restrict__ fb2,
                                                  float* __restrict__ out) {
    int b = blockIdx.x;
    int j = threadIdx.x;  // 0..63 hidden unit
    float h = fb1[j];
    for (int k = 0; k < F; ++k)
        h = fmaf(g[b * F + k], fw1[k * 64 + j], h);
    h = fmaxf(h, 0.f) * fw2[j];
#pragma unroll
    for (int w = 32; w >= 1; w >>= 1) h += __shfl_xor(h, w, 64);
    if (j == 0) out[b] = h + fb2[0];
}

// ---------------- launcher ----------------

extern "C" void kernel_launch(void* const* d_in, const int* in_sizes, int n_in,
                              void* d_out, int out_size, void* d_ws, size_t ws_size,
                              hipStream_t stream) {
    const float* x    = (const float*)d_in[0];
    const int* eidx   = (const int*)d_in[1];
    const int* batch  = (const int*)d_in[2];
    const float* W1   = (const float*)d_in[3];
    const float* b1   = (const float*)d_in[4];
    const float* W2   = (const float*)d_in[5];
    const float* b2   = (const float*)d_in[6];
    const float* W3   = (const float*)d_in[7];
    const float* b3   = (const float*)d_in[8];
    const float* fw1  = (const float*)d_in[9];
    const float* fb1  = (const float*)d_in[10];
    const float* fw2  = (const float*)d_in[11];
    const float* fb2  = (const float*)d_in[12];
    float* out        = (float*)d_out;

    const int* src = eidx;            // edge_index[0]
    const int* dst = eidx + N_EDGES;  // edge_index[1]

    // workspace carve-up
    char* ws = (char*)d_ws;
    size_t p = 0;
    auto alloc = [&](size_t bytes) -> void* {
        void* r = ws + p;
        p = (p + bytes + 255) & ~(size_t)255;
        return r;
    };
    int*      deg    = (int*)     alloc((size_t)N_NODES * 4);
    float*    dinv   = (float*)   alloc((size_t)N_NODES * 4);
    int*      off    = (int*)     alloc((size_t)(N_NODES + 4) * 4);
    int*      cursor = (int*)     alloc((size_t)N_NODES * 4);
    int*      srcs   = (int*)     alloc((size_t)N_EDGES * 4);
    int*      bsum   = (int*)     alloc((size_t)SCAN_NB * 4);
    int*      bexcl  = (int*)     alloc((size_t)SCAN_NB * 4);
    unsigned* HsPk   = (unsigned*)alloc((size_t)N_NODES * FH * 4);  // packed bf16 messages
    float*    bufB   = (float*)   alloc((size_t)N_NODES * F * 4);   // f32 layer output
    float*    psums  = (float*)   alloc((size_t)B_GRAPHS * F * 4);
    int*      pcnts  = (int*)     alloc((size_t)B_GRAPHS * 4);
    float*    gpool  = (float*)   alloc((size_t)B_GRAPHS * F * 4);
    (void)ws_size;

    const int TB = 256;
    const int nblk_N = (N_NODES + TB - 1) / TB;
    const int nblk_E = (N_EDGES + TB - 1) / TB;
    const int gemm_blocks = (N_NODES + 127) / 128;
    const int agg_blocks = (N_NODES + 3) / 4;
    const int pool_blocks = (N_NODES + POOL_CHUNK - 1) / POOL_CHUNK;

    // 1. degrees
    zero_i32<<<nblk_N, TB, 0, stream>>>(deg, N_NODES);
    deg_count<<<nblk_E, TB, 0, stream>>>(dst, deg);
    dinv_kernel<<<nblk_N, TB, 0, stream>>>(deg, dinv);

    // 2. CSR (two-level scan + scatter)
    scan1<<<SCAN_NB, 256, 0, stream>>>(deg, off, bsum);
    scan2<<<1, 64, 0, stream>>>(bsum, bexcl, off);
    scan3<<<SCAN_NB, 256, 0, stream>>>(off, cursor, bexcl);
    scatter_kernel<<<nblk_E, TB, 0, stream>>>(src, dst, cursor, srcs);

    // 3. layer 1
    gemm_scale<<<gemm_blocks, 256, 0, stream>>>(x, W1, dinv, HsPk, N_NODES);
    aggregate_bf16<<<agg_blocks, 256, 0, stream>>>(HsPk, off, srcs, dinv, b1, bufB, 1);

    // 4. layer 2
    gemm_scale<<<gemm_blocks, 256, 0, stream>>>(bufB, W2, dinv, HsPk, N_NODES);
    aggregate_bf16<<<agg_blocks, 256, 0, stream>>>(HsPk, off, srcs, dinv, b2, bufB, 1);

    // 5. layer 3 (no relu)
    gemm_scale<<<gemm_blocks, 256, 0, stream>>>(bufB, W3, dinv, HsPk, N_NODES);
    aggregate_bf16<<<agg_blocks, 256, 0, stream>>>(HsPk, off, srcs, dinv, b3, bufB, 0);

    // 6. mean pool (parallel two-stage)
    zero_f32<<<(B_GRAPHS * F + TB - 1) / TB, TB, 0, stream>>>(psums, B_GRAPHS * F);
    zero_i32<<<1, B_GRAPHS, 0, stream>>>(pcnts, B_GRAPHS);
    pool_partial<<<pool_blocks, 128, 0, stream>>>(bufB, batch, psums, pcnts);
    pool_finalize<<<B_GRAPHS, 128, 0, stream>>>(psums, pcnts, gpool);

    // 7. head MLP
    head_kernel<<<B_GRAPHS, 64, 0, stream>>>(gpool, fw1, fb1, fw2, fb2, out);
}

// Round 5
// 439.624 us; speedup vs baseline: 1.9512x; 1.1969x over previous
//
#include <hip/hip_runtime.h>
#include <math.h>

#define N_NODES 50000
#define N_EDGES 800000
#define F 128
#define FH 64               // packed bf16x2 words per row
#define B_GRAPHS 64
#define SCAN_NB 49          // ceil(50000 / 1024)
#define N_INT4 12500        // N_NODES / 4

// ---------------- bf16 pack/unpack ----------------

__device__ __forceinline__ unsigned pack_bf16x2(float a, float b) {
    unsigned ua = __float_as_uint(a);
    unsigned ub = __float_as_uint(b);
    ua += 0x7fffu + ((ua >> 16) & 1u);   // RNE
    ub += 0x7fffu + ((ub >> 16) & 1u);
    return (ua >> 16) | (ub & 0xffff0000u);
}

__device__ __forceinline__ float2 unpack_bf16x2(unsigned p) {
    return make_float2(__uint_as_float(p << 16),
                       __uint_as_float(p & 0xffff0000u));
}

// ---------------- utility ----------------

__global__ __launch_bounds__(256) void zero_i32(int* p, int n) {
    int i = blockIdx.x * blockDim.x + threadIdx.x;
    if (i < n) p[i] = 0;
}

__global__ __launch_bounds__(256) void zero_f32(float* p, int n) {
    int i = blockIdx.x * blockDim.x + threadIdx.x;
    if (i < n) p[i] = 0.f;
}

// ---------------- degree / norm ----------------

__global__ __launch_bounds__(256) void deg_count(const int* __restrict__ dst,
                                                 int* __restrict__ deg) {
    int e = blockIdx.x * blockDim.x + threadIdx.x;
    if (e < N_EDGES) atomicAdd(&deg[dst[e]], 1);
}

__global__ __launch_bounds__(256) void dinv_kernel(const int* __restrict__ deg,
                                                   float* __restrict__ dinv) {
    int i = blockIdx.x * blockDim.x + threadIdx.x;
    if (i < N_NODES) dinv[i] = rsqrtf((float)(deg[i] + 1));  // +1 self-loop
}

// ---------------- CSR build: two-level scan ----------------

__global__ __launch_bounds__(256) void scan1(const int* __restrict__ deg,
                                             int* __restrict__ off,
                                             int* __restrict__ bsum) {
    __shared__ int wsum[4];
    int b = blockIdx.x, t = threadIdx.x;
    int i4 = b * 256 + t;
    int4 v = make_int4(0, 0, 0, 0);
    if (i4 < N_INT4) v = ((const int4*)deg)[i4];
    int s = v.x + v.y + v.z + v.w;
    int lane = t & 63;
    int incl = s;
#pragma unroll
    for (int d = 1; d < 64; d <<= 1) {
        int u = __shfl_up(incl, d, 64);
        if (lane >= d) incl += u;
    }
    int wave = t >> 6;
    if (lane == 63) wsum[wave] = incl;
    __syncthreads();
    int woff = 0;
#pragma unroll
    for (int w = 0; w < 3; ++w) if (w < wave) woff += wsum[w];
    int texcl = woff + incl - s;
    int4 o;
    o.x = texcl;
    o.y = o.x + v.x;
    o.z = o.y + v.y;
    o.w = o.z + v.z;
    if (i4 < N_INT4) ((int4*)off)[i4] = o;
    if (t == 255) bsum[b] = woff + incl;  // block total
}

__global__ __launch_bounds__(64) void scan2(const int* __restrict__ bsum,
                                            int* __restrict__ bexcl,
                                            int* __restrict__ off) {
    int t = threadIdx.x;
    int v = (t < SCAN_NB) ? bsum[t] : 0;
    int incl = v;
#pragma unroll
    for (int d = 1; d < 64; d <<= 1) {
        int u = __shfl_up(incl, d, 64);
        if (t >= d) incl += u;
    }
    if (t < SCAN_NB) bexcl[t] = incl - v;
    if (t == 63) off[N_NODES] = incl;  // grand total (= N_EDGES)
}

__global__ __launch_bounds__(256) void scan3(int* __restrict__ off,
                                             int* __restrict__ cursor,
                                             const int* __restrict__ bexcl) {
    int b = blockIdx.x, t = threadIdx.x;
    int i4 = b * 256 + t;
    if (i4 >= N_INT4) return;
    int add = bexcl[b];
    int4 o = ((int4*)off)[i4];
    o.x += add; o.y += add; o.z += add; o.w += add;
    ((int4*)off)[i4] = o;
    ((int4*)cursor)[i4] = o;
}

__global__ __launch_bounds__(256) void scatter_kernel(const int* __restrict__ src,
                                                      const int* __restrict__ dst,
                                                      int* __restrict__ cursor,
                                                      int* __restrict__ srcs) {
    int e = blockIdx.x * blockDim.x + threadIdx.x;
    if (e < N_EDGES) {
        int d = dst[e];
        int p = atomicAdd(&cursor[d], 1);
        srcs[p] = src[e];
    }
}

// ---------------- GEMM: Hs[i][c] = bf16( dinv[i] * sum_k X[i][k] W[k][c] ) ----------------

__global__ __launch_bounds__(256) void gemm_scale(const float* __restrict__ X,
                                                  const float* __restrict__ W,
                                                  const float* __restrict__ dinv,
                                                  unsigned* __restrict__ outp,  // packed bf16x2 [nrows][64]
                                                  int nrows) {
    __shared__ float xT[32][F + 4];  // [k][row], padded
    __shared__ float wS[32][F];      // [k][col]
    const int block_row = blockIdx.x * 128;
    const int tid = threadIdx.x;
    const int rg = (tid >> 4) * 8;   // row group 0..120
    const int cg = (tid & 15) * 8;   // col group 0..120

    float acc[8][8];
#pragma unroll
    for (int i = 0; i < 8; ++i)
#pragma unroll
        for (int j = 0; j < 8; ++j) acc[i][j] = 0.f;

    for (int k0 = 0; k0 < F; k0 += 32) {
#pragma unroll
        for (int l = 0; l < 4; ++l) {
            int idx = tid + l * 256;          // 0..1023
            int r = idx >> 3;                 // 0..127
            int kq = (idx & 7) * 4;           // 0,4,...,28
            int row = block_row + r;
            float4 v = make_float4(0.f, 0.f, 0.f, 0.f);
            if (row < nrows)
                v = *(const float4*)&X[(size_t)row * F + k0 + kq];
            xT[kq + 0][r] = v.x;
            xT[kq + 1][r] = v.y;
            xT[kq + 2][r] = v.z;
            xT[kq + 3][r] = v.w;
        }
#pragma unroll
        for (int l = 0; l < 4; ++l) {
            int idx = tid + l * 256;          // 0..1023
            int kk = idx >> 5;                // 0..31
            int cq = (idx & 31) * 4;          // 0..124
            *(float4*)&wS[kk][cq] = *(const float4*)&W[(size_t)(k0 + kk) * F + cq];
        }
        __syncthreads();
#pragma unroll
        for (int k = 0; k < 32; ++k) {
            float a[8], bw[8];
            *(float4*)&a[0] = *(const float4*)&xT[k][rg];
            *(float4*)&a[4] = *(const float4*)&xT[k][rg + 4];
            *(float4*)&bw[0] = *(const float4*)&wS[k][cg];
            *(float4*)&bw[4] = *(const float4*)&wS[k][cg + 4];
#pragma unroll
            for (int i = 0; i < 8; ++i)
#pragma unroll
                for (int j = 0; j < 8; ++j)
                    acc[i][j] = fmaf(a[i], bw[j], acc[i][j]);
        }
        __syncthreads();
    }
#pragma unroll
    for (int i = 0; i < 8; ++i) {
        int row = block_row + rg + i;
        if (row < nrows) {
            float s = dinv[row];
            uint4 o;
            o.x = pack_bf16x2(acc[i][0] * s, acc[i][1] * s);
            o.y = pack_bf16x2(acc[i][2] * s, acc[i][3] * s);
            o.z = pack_bf16x2(acc[i][4] * s, acc[i][5] * s);
            o.w = pack_bf16x2(acc[i][6] * s, acc[i][7] * s);
            *(uint4*)&outp[(size_t)row * FH + (cg >> 1)] = o;
        }
    }
}

// ------- shared edge-sum core: acc = Hs[node] + sum Hs[srcs], packed bf16 rows -------

__device__ __forceinline__ float2 edge_sum(const unsigned* __restrict__ Hs,
                                           const int* __restrict__ off,
                                           const int* __restrict__ srcs,
                                           int node, int lane) {
    float2 acc = unpack_bf16x2(Hs[(size_t)node * FH + lane]);  // self term
    int e0 = off[node], e1 = off[node + 1];
    int e = e0;
    for (; e + 3 < e1; e += 4) {
        int s0 = srcs[e], s1 = srcs[e + 1], s2 = srcs[e + 2], s3 = srcs[e + 3];
        float2 v0 = unpack_bf16x2(Hs[(size_t)s0 * FH + lane]);
        float2 v1 = unpack_bf16x2(Hs[(size_t)s1 * FH + lane]);
        float2 v2 = unpack_bf16x2(Hs[(size_t)s2 * FH + lane]);
        float2 v3 = unpack_bf16x2(Hs[(size_t)s3 * FH + lane]);
        acc.x += (v0.x + v1.x) + (v2.x + v3.x);
        acc.y += (v0.y + v1.y) + (v2.y + v3.y);
    }
    for (; e < e1; ++e) {
        float2 v = unpack_bf16x2(Hs[(size_t)srcs[e] * FH + lane]);
        acc.x += v.x;
        acc.y += v.y;
    }
    return acc;
}

// ------- layers 1,2: out[i] = relu(dinv[i]*acc + b), f32 out -------

__global__ __launch_bounds__(256) void aggregate_bf16(const unsigned* __restrict__ Hs,
                                                      const int* __restrict__ off,
                                                      const int* __restrict__ srcs,
                                                      const float* __restrict__ dinv,
                                                      const float* __restrict__ bias,
                                                      float* __restrict__ out) {
    int node = blockIdx.x * 4 + (threadIdx.x >> 6);
    if (node >= N_NODES) return;
    int lane = threadIdx.x & 63;
    float2 acc = edge_sum(Hs, off, srcs, node, lane);
    float d = dinv[node];
    float o0 = fmaxf(fmaf(d, acc.x, bias[2 * lane]), 0.f);
    float o1 = fmaxf(fmaf(d, acc.y, bias[2 * lane + 1]), 0.f);
    *(float2*)&out[(size_t)node * F + 2 * lane] = make_float2(o0, o1);
}

// ------- layer 3 fused with mean-pool accumulation: psums[batch[i]] += dinv*acc+b -------
// 4 nodes/block; LDS-reduce same-graph rows, then one atomicAdd per feature.

__global__ __launch_bounds__(256) void aggregate_pool(const unsigned* __restrict__ Hs,
                                                      const int* __restrict__ off,
                                                      const int* __restrict__ srcs,
                                                      const float* __restrict__ dinv,
                                                      const float* __restrict__ bias,
                                                      const int* __restrict__ batch,
                                                      float* __restrict__ psums) {
    int wave = threadIdx.x >> 6;
    int lane = threadIdx.x & 63;
    int node = blockIdx.x * 4 + wave;   // grid sized so node always < N_NODES

    __shared__ float2 red[4][64];
    __shared__ int bids[4];

    float2 acc = edge_sum(Hs, off, srcs, node, lane);
    float d = dinv[node];
    float o0 = fmaf(d, acc.x, bias[2 * lane]);
    float o1 = fmaf(d, acc.y, bias[2 * lane + 1]);
    red[wave][lane] = make_float2(o0, o1);
    if (lane == 0) bids[wave] = batch[node];
    __syncthreads();

    if (wave == 0) {
        int b0 = bids[0];
        bool same = (b0 == bids[1]) && (b0 == bids[2]) && (b0 == bids[3]);
        if (same) {
            float2 s = red[0][lane];
            s.x += red[1][lane].x + red[2][lane].x + red[3][lane].x;
            s.y += red[1][lane].y + red[2][lane].y + red[3][lane].y;
            atomicAdd(&psums[b0 * F + 2 * lane], s.x);
            atomicAdd(&psums[b0 * F + 2 * lane + 1], s.y);
        } else {
#pragma unroll
            for (int w = 0; w < 4; ++w) {
                atomicAdd(&psums[bids[w] * F + 2 * lane], red[w][lane].x);
                atomicAdd(&psums[bids[w] * F + 2 * lane + 1], red[w][lane].y);
            }
        }
    }
}

// ---------------- pool finalize: divide by counts (binary search on sorted batch) ----------------

__device__ __forceinline__ int lower_bound_dev(const int* __restrict__ a, int n, int v) {
    int lo = 0, hi = n;
    while (lo < hi) {
        int m = (lo + hi) >> 1;
        if (a[m] < v) lo = m + 1; else hi = m;
    }
    return lo;
}

__global__ __launch_bounds__(128) void pool_finalize(const float* __restrict__ psums,
                                                     const int* __restrict__ batch,
                                                     float* __restrict__ g) {
    int b = blockIdx.x;
    int f = threadIdx.x;
    int lo = lower_bound_dev(batch, N_NODES, b);
    int hi = lower_bound_dev(batch, N_NODES, b + 1);
    float cnt = (float)(hi - lo);
    g[b * F + f] = psums[b * F + f] / fmaxf(cnt, 1.0f);
}

// ---------------- head MLP: out[b] = relu(g fw1 + fb1) fw2 + fb2 ----------------

__global__ __launch_bounds__(64) void head_kernel(const float* __restrict__ g,
                                                  const float* __restrict__ fw1,
                                                  const float* __restrict__ fb1,
                                                  const float* __restrict__ fw2,
                                                  const float* __restrict__ fb2,
                                                  float* __restrict__ out) {
    int b = blockIdx.x;
    int j = threadIdx.x;  // 0..63 hidden unit
    float h = fb1[j];
    for (int k = 0; k < F; ++k)
        h = fmaf(g[b * F + k], fw1[k * 64 + j], h);
    h = fmaxf(h, 0.f) * fw2[j];
#pragma unroll
    for (int w = 32; w >= 1; w >>= 1) h += __shfl_xor(h, w, 64);
    if (j == 0) out[b] = h + fb2[0];
}

// ---------------- launcher ----------------

extern "C" void kernel_launch(void* const* d_in, const int* in_sizes, int n_in,
                              void* d_out, int out_size, void* d_ws, size_t ws_size,
                              hipStream_t stream) {
    const float* x    = (const float*)d_in[0];
    const int* eidx   = (const int*)d_in[1];
    const int* batch  = (const int*)d_in[2];
    const float* W1   = (const float*)d_in[3];
    const float* b1   = (const float*)d_in[4];
    const float* W2   = (const float*)d_in[5];
    const float* b2   = (const float*)d_in[6];
    const float* W3   = (const float*)d_in[7];
    const float* b3   = (const float*)d_in[8];
    const float* fw1  = (const float*)d_in[9];
    const float* fb1  = (const float*)d_in[10];
    const float* fw2  = (const float*)d_in[11];
    const float* fb2  = (const float*)d_in[12];
    float* out        = (float*)d_out;

    const int* src = eidx;            // edge_index[0]
    const int* dst = eidx + N_EDGES;  // edge_index[1]

    // workspace carve-up
    char* ws = (char*)d_ws;
    size_t p = 0;
    auto alloc = [&](size_t bytes) -> void* {
        void* r = ws + p;
        p = (p + bytes + 255) & ~(size_t)255;
        return r;
    };
    int*      deg    = (int*)     alloc((size_t)N_NODES * 4);
    float*    dinv   = (float*)   alloc((size_t)N_NODES * 4);
    int*      off    = (int*)     alloc((size_t)(N_NODES + 4) * 4);
    int*      cursor = (int*)     alloc((size_t)N_NODES * 4);
    int*      srcs   = (int*)     alloc((size_t)N_EDGES * 4);
    int*      bsum   = (int*)     alloc((size_t)SCAN_NB * 4);
    int*      bexcl  = (int*)     alloc((size_t)SCAN_NB * 4);
    unsigned* HsPk   = (unsigned*)alloc((size_t)N_NODES * FH * 4);  // packed bf16 messages
    float*    bufB   = (float*)   alloc((size_t)N_NODES * F * 4);   // f32 layer output
    float*    psums  = (float*)   alloc((size_t)B_GRAPHS * F * 4);
    float*    gpool  = (float*)   alloc((size_t)B_GRAPHS * F * 4);
    (void)ws_size;

    const int TB = 256;
    const int nblk_N = (N_NODES + TB - 1) / TB;
    const int nblk_E = (N_EDGES + TB - 1) / TB;
    const int gemm_blocks = (N_NODES + 127) / 128;
    const int agg_blocks = (N_NODES + 3) / 4;   // 12500, exact

    // 1. degrees
    zero_i32<<<nblk_N, TB, 0, stream>>>(deg, N_NODES);
    deg_count<<<nblk_E, TB, 0, stream>>>(dst, deg);
    dinv_kernel<<<nblk_N, TB, 0, stream>>>(deg, dinv);

    // 2. CSR (two-level scan + scatter)
    scan1<<<SCAN_NB, 256, 0, stream>>>(deg, off, bsum);
    scan2<<<1, 64, 0, stream>>>(bsum, bexcl, off);
    scan3<<<SCAN_NB, 256, 0, stream>>>(off, cursor, bexcl);
    scatter_kernel<<<nblk_E, TB, 0, stream>>>(src, dst, cursor, srcs);

    // 3. layer 1
    gemm_scale<<<gemm_blocks, 256, 0, stream>>>(x, W1, dinv, HsPk, N_NODES);
    aggregate_bf16<<<agg_blocks, 256, 0, stream>>>(HsPk, off, srcs, dinv, b1, bufB);

    // 4. layer 2
    gemm_scale<<<gemm_blocks, 256, 0, stream>>>(bufB, W2, dinv, HsPk, N_NODES);
    aggregate_bf16<<<agg_blocks, 256, 0, stream>>>(HsPk, off, srcs, dinv, b2, bufB);

    // 5. layer 3 fused with pool accumulation
    gemm_scale<<<gemm_blocks, 256, 0, stream>>>(bufB, W3, dinv, HsPk, N_NODES);
    zero_f32<<<(B_GRAPHS * F + TB - 1) / TB, TB, 0, stream>>>(psums, B_GRAPHS * F);
    aggregate_pool<<<agg_blocks, 256, 0, stream>>>(HsPk, off, srcs, dinv, b3, batch, psums);

    // 6. finalize mean + head MLP
    pool_finalize<<<B_GRAPHS, 128, 0, stream>>>(psums, batch, gpool);
    head_kernel<<<B_GRAPHS, 64, 0, stream>>>(gpool, fw1, fb1, fw2, fb2, out);
}